// Round 11
// baseline (259.352 us; speedup 1.0000x reference)
//
#include <hip/hip_runtime.h>

// Problem constants
#define BB 32
#define LL 256
#define NN 1024
#define BL 8192         // B*L
#define TOPK 307        // int(1024*0.3)
#define SPLITK 16
#define NTILES 36       // upper-tri 128x128 tiles of 1024x1024
#define PART_STRIDE ((size_t)NTILES * 16384)

typedef unsigned short ushort_t;
typedef unsigned long long u64;
typedef __bf16 bf16x8 __attribute__((ext_vector_type(8)));
typedef float f32x4 __attribute__((ext_vector_type(4)));
typedef unsigned short us4 __attribute__((ext_vector_type(4)));

// round-to-nearest-even float -> bf16
__device__ __forceinline__ ushort_t f2bf(float f) {
    unsigned int u = __float_as_uint(f);
    u += 0x7FFFu + ((u >> 16) & 1u);
    return (ushort_t)(u >> 16);
}
__device__ __forceinline__ float bf2f(ushort_t h) {
    return __uint_as_float(((unsigned int)h) << 16);
}

// async global->LDS DMA, 16B/lane; LDS dest = wave-uniform base + lane*16
__device__ __forceinline__ void gload16(const void* g, const void* l) {
    __builtin_amdgcn_global_load_lds(
        (__attribute__((address_space(1))) void*)(unsigned long long)g,
        (__attribute__((address_space(3))) void*)(unsigned int)(unsigned long long)l,
        16, 0, 0);
}

// LDS bank-conflict swizzle: LDS (row, quad-slot qp) holds global k-quad
// g = (qp - (row>>1)) & 3. Writer thread t (row=t>>2, qp=t&3) sources quad
// ((t&3) - ((t>>2)>>1)) & 3; rows +64 give the same value (32 ≡ 0 mod 4).
// Reader: slot for quad g of row r is (g + (r>>1)) & 3 -> conflict-free for
// the 16x16 fragment read (measured 0 SQ_LDS_BANK_CONFLICT). NOTE: the
// 32x32x16 fragment read pattern under this swizzle measured 2.36M
// conflicts/dispatch (R9) -- do NOT switch to 32x32 without a new layout.

// ---------------------------------------------------------------------------
// K1 (fused norms + transpose): one pass over x. Emits node-major bf16 xhi/xlo
// (normalized hi/lo split) and fp32 nrm[b][n]. ushort4 write phase.
// Extra slab blockIdx.x==32: WT[o][l] = bf16(W[l][o]) (fused to cut a dispatch).
__global__ __launch_bounds__(256) void k_prep(const float* __restrict__ x,
                                              ushort_t* __restrict__ xhi,
                                              ushort_t* __restrict__ xlo,
                                              float* __restrict__ nrm,
                                              const float* __restrict__ W,
                                              ushort_t* __restrict__ WT) {
    __shared__ float tile[32][268];   // [n_local][l], 268: %32=12 (<=4-way), 16B-aligned rows
    __shared__ float red[32][33];     // [lr][n_local]
    __shared__ float inv[32];
    __shared__ float wt[32][33];
    const int t = threadIdx.x;
    if (blockIdx.x == 32) {           // W^T slab: 32 blocks x 2 tiles of 32x32
        const int tx = t & 31, ty = t >> 5;
#pragma unroll
        for (int s = 0; s < 2; ++s) {
            const int id = blockIdx.y * 2 + s;   // [0,64)
            const int c0 = (id & 7) * 32;        // o
            const int r0 = (id >> 3) * 32;       // l
#pragma unroll
            for (int j = 0; j < 32; j += 8)
                wt[ty + j][tx] = W[(size_t)(r0 + ty + j) * LL + c0 + tx];
            __syncthreads();
#pragma unroll
            for (int j = 0; j < 32; j += 8)
                WT[(size_t)(c0 + ty + j) * LL + r0 + tx] = f2bf(wt[tx][ty + j]);
            __syncthreads();
        }
        return;
    }
    const int n0 = blockIdx.x * 32, b = blockIdx.y;
    const int qn = (t & 7) * 4, lr = t >> 3;
    const float* xb = x + (size_t)b * LL * NN + n0;
    float p0 = 0.f, p1 = 0.f, p2 = 0.f, p3 = 0.f;
#pragma unroll
    for (int j = 0; j < 8; ++j) {
        int l = lr + 32 * j;
        f32x4 v = *(const f32x4*)&xb[(size_t)l * NN + qn];
        tile[qn + 0][l] = v[0];
        tile[qn + 1][l] = v[1];
        tile[qn + 2][l] = v[2];
        tile[qn + 3][l] = v[3];
        p0 = fmaf(v[0], v[0], p0);
        p1 = fmaf(v[1], v[1], p1);
        p2 = fmaf(v[2], v[2], p2);
        p3 = fmaf(v[3], v[3], p3);
    }
    red[lr][qn + 0] = p0;
    red[lr][qn + 1] = p1;
    red[lr][qn + 2] = p2;
    red[lr][qn + 3] = p3;
    __syncthreads();
    if (t < 32) {
        float acc = 0.f;
#pragma unroll
        for (int j = 0; j < 32; ++j) acc += red[j][t];
        float nv = fmaxf(sqrtf(acc), 1e-12f);
        nrm[b * NN + n0 + t] = nv;
        inv[t] = 1.0f / nv;
    }
    __syncthreads();
    // write phase: thread handles 4 consecutive l (ushort4 stores), 8 n per wave
    const int l4 = (t & 63) * 4, wv = t >> 6;
#pragma unroll
    for (int j = 0; j < 8; ++j) {
        const int nl = wv * 8 + j;
        f32x4 v = *(const f32x4*)&tile[nl][l4];
        const float iv = inv[nl];
        us4 hi, lo;
#pragma unroll
        for (int i = 0; i < 4; ++i) {
            float sc = v[i] * iv;
            ushort_t h = f2bf(sc);
            hi[i] = h;
            lo[i] = f2bf(sc - bf2f(h));
        }
        size_t o = (size_t)(n0 + nl) * BL + b * LL + l4;
        *(us4*)&xhi[o] = hi;
        *(us4*)&xlo[o] = lo;
    }
}

// ---------------------------------------------------------------------------
// GEMM1: partial sims, split-bf16 (hi*hi + hi*lo + lo*hi), 16x16x32 MFMA.
// v4: 3 sequential PHASES (one product pass each) sharing one 32KB dbuf pair
// -> LDS 64KB->32KB -> 5 blocks/CU (was 2; R10 measured Occupancy 11.5%,
// MfmaUtil 25% = occupancy-starved barrier drain). Each phase is the proven
// m97-shaped loop (4 gload16 + 8 ds_read_b128 + 16 MFMA per iter, 0 bank
// conflicts); only the global source pointers differ (compile-time via
// unrolled phase loop). acc persists in registers across phases.
// Upper-tri 128-tiles, splitK=16, XCD swizzle (FETCH ~20MB, L2-resident).
__global__ __launch_bounds__(256, 5) void k_sim_mfma(const ushort_t* __restrict__ Xhi,
                                                     const ushort_t* __restrict__ Xlo,
                                                     float* __restrict__ part) {
    __shared__ ushort_t sA[2][4096], sB[2][4096];
    const int t = threadIdx.x, l = t & 63, w = t >> 6;
    const int bid = blockIdx.x;
    const int swz = (bid & 7) * 72 + (bid >> 3);   // bijective: 576 = 8*72
    const int z = swz / NTILES;
    const int tid36 = swz - z * NTILES;
    int id = tid36, ti = 0;                    // [0,36) -> upper-tri (ti,tj)
    while (id >= 8 - ti) { id -= 8 - ti; ++ti; }
    const int tj = ti + id;
    const int i0 = ti * 128, j0 = tj * 128;
    const int it0 = 16 * z, it1 = it0 + 16;
    const int ra = t >> 2;
    const int rb = ra + 64;
    const int qa = ((((t & 3) - (ra >> 1)) & 3)) * 8;   // swizzled source quad
    const int lb0 = 512 * w, lb1 = 512 * (w + 4);
    const int wr = (w >> 1) * 64, wc = (w & 1) * 64;
    const int lrow = l & 15, g = l >> 4;
    const ushort_t* Ah = Xhi + (size_t)i0 * BL;
    const ushort_t* Al = Xlo + (size_t)i0 * BL;
    const ushort_t* Bh = Xhi + (size_t)j0 * BL;
    const ushort_t* Bl = Xlo + (size_t)j0 * BL;

    // hoisted swizzled fragment offsets
    int offA[4], offB[4];
#pragma unroll
    for (int r = 0; r < 4; ++r) {
        int row = wr + r * 16 + lrow;
        offA[r] = row * 32 + (((g + (row >> 1)) & 3) * 8);
        row = wc + r * 16 + lrow;
        offB[r] = row * 32 + (((g + (row >> 1)) & 3) * 8);
    }

    auto dma = [&](const ushort_t* pa, const ushort_t* pb, int it, int buf) {
        const int k0 = it * 32;
        gload16(pa + (size_t)ra * BL + k0 + qa, &sA[buf][lb0]);
        gload16(pa + (size_t)rb * BL + k0 + qa, &sA[buf][lb1]);
        gload16(pb + (size_t)ra * BL + k0 + qa, &sB[buf][lb0]);
        gload16(pb + (size_t)rb * BL + k0 + qa, &sB[buf][lb1]);
    };

    f32x4 acc[4][4] = {};
#pragma unroll
    for (int ph = 0; ph < 3; ++ph) {
        const ushort_t* pa = (ph == 2) ? Al : Ah;   // compile-time after unroll
        const ushort_t* pb = (ph == 1) ? Bl : Bh;
        __syncthreads();                 // prior phase's buf0 reads complete
        dma(pa, pb, it0, 0);
        for (int it = it0; it < it1; ++it) {
            const int cur = (it - it0) & 1;
            __syncthreads();                         // drains DMA into buf[cur]
            if (it + 1 < it1) dma(pa, pb, it + 1, cur ^ 1);
            bf16x8 af[4], bf_[4];
#pragma unroll
            for (int r = 0; r < 4; ++r)
                af[r] = *(const bf16x8*)&sA[cur][offA[r]];
#pragma unroll
            for (int c = 0; c < 4; ++c)
                bf_[c] = *(const bf16x8*)&sB[cur][offB[c]];
#pragma unroll
            for (int r = 0; r < 4; ++r)
#pragma unroll
                for (int c = 0; c < 4; ++c)
                    acc[r][c] = __builtin_amdgcn_mfma_f32_16x16x32_bf16(af[r], bf_[c], acc[r][c], 0, 0, 0);
        }
    }
    float* P = part + (size_t)z * PART_STRIDE + (size_t)tid36 * 16384;
    const int orow = wr + (l >> 4) * 4;
    const int ocol = wc + lrow;
#pragma unroll
    for (int r = 0; r < 4; ++r)
#pragma unroll
        for (int c = 0; c < 4; ++c)
#pragma unroll
            for (int p = 0; p < 4; ++p)
                P[(size_t)(orow + r * 16 + p) * 128 + ocol + c * 16] = acc[r][c][p];
}

// ---------------------------------------------------------------------------
// Reduce partials -> sim (both triangles, scaled by 1/B). float4 I/O.
__global__ __launch_bounds__(256) void k_reduce(const float* __restrict__ part,
                                                float* __restrict__ sim) {
    __shared__ float tl[64][65];
    const int t = threadIdx.x;
    int id = blockIdx.x, ti = 0;
    while (id >= 8 - ti) { id -= 8 - ti; ++ti; }
    const int tj = ti + id;
    const int q = blockIdx.y;
    const int r0 = (q >> 1) * 64, c0 = (q & 1) * 64;
    const float* Pu = part + (size_t)blockIdx.x * 16384;
    const int fr = t & 15, rq = t >> 4;   // fr: float4-col, rq: row within 16
#pragma unroll
    for (int e = 0; e < 4; ++e) {
        int r = e * 16 + rq;
        f32x4 s = {};
#pragma unroll
        for (int z = 0; z < SPLITK; ++z)
            s += *(const f32x4*)&Pu[(size_t)z * PART_STRIDE + (size_t)(r0 + r) * 128 + c0 + fr * 4];
        s *= (1.0f / BB);
        *(f32x4*)&sim[(size_t)(ti * 128 + r0 + r) * NN + tj * 128 + c0 + fr * 4] = s;
        tl[r][fr * 4 + 0] = s[0];
        tl[r][fr * 4 + 1] = s[1];
        tl[r][fr * 4 + 2] = s[2];
        tl[r][fr * 4 + 3] = s[3];
    }
    __syncthreads();
    if (ti != tj) {
#pragma unroll
        for (int e = 0; e < 16; ++e) {
            int li = e * 256 + t;
            int cc = li >> 6, rr = li & 63;   // rr consecutive -> coalesced
            sim[(size_t)(tj * 128 + c0 + cc) * NN + ti * 128 + r0 + rr] = tl[rr][cc];
        }
    }
}

// ---------------------------------------------------------------------------
// K3: exact top-307 per row (excl self), one wave/row, ballot binary search.
// Named scalars (register-resident), float4 I/O. Block 0 also zeroes deg
// (replaces a hipMemsetAsync dispatch; stream order covers k_deg's atomics).
#define FOR16(M) M(0) M(1) M(2) M(3) M(4) M(5) M(6) M(7) \
                 M(8) M(9) M(10) M(11) M(12) M(13) M(14) M(15)
__global__ __launch_bounds__(256, 1) void k_topk(const float* __restrict__ sim,
                                                 float* __restrict__ A,
                                                 float* __restrict__ deg) {
    const int t = threadIdx.x, l = t & 63, w = t >> 6;
    if (blockIdx.x == 0) {
        f32x4 zz = {};
        *(f32x4*)&deg[t * 4] = zz;
    }
    const int n = blockIdx.x * 4 + w;
    const float* row = sim + (size_t)n * NN + l * 16;
    f32x4 v0 = *(const f32x4*)(row + 0);
    f32x4 v1 = *(const f32x4*)(row + 4);
    f32x4 v2 = *(const f32x4*)(row + 8);
    f32x4 v3 = *(const f32x4*)(row + 12);
    const int selfe = n - l * 16;   // in [0,16) iff this lane holds the diagonal
#define MKK(i, vec, c) unsigned k##i; { unsigned u = __float_as_uint(vec[c]); \
    unsigned kk = (u & 0x80000000u) ? ~u : (u | 0x80000000u); \
    k##i = (selfe == i) ? 0u : kk; }
    MKK(0, v0, 0)  MKK(1, v0, 1)  MKK(2, v0, 2)  MKK(3, v0, 3)
    MKK(4, v1, 0)  MKK(5, v1, 1)  MKK(6, v1, 2)  MKK(7, v1, 3)
    MKK(8, v2, 0)  MKK(9, v2, 1)  MKK(10, v2, 2) MKK(11, v2, 3)
    MKK(12, v3, 0) MKK(13, v3, 1) MKK(14, v3, 2) MKK(15, v3, 3)
#undef MKK
    unsigned cur = 0u;
    for (int bit = 31; bit >= 0; --bit) {
        unsigned cand = cur | (1u << bit);
        int c = 0;
#define CNT(i) c += __popcll(__ballot(k##i >= cand));
        FOR16(CNT)
#undef CNT
        if (c >= TOPK) cur = cand;
    }
    const unsigned T = cur;
    int cgt = 0;
#define CGT(i) cgt += __popcll(__ballot(k##i > T));
    FOR16(CGT)
#undef CGT
    const int need = TOPK - cgt;
    const u64 mymask = (l == 0) ? 0ull : (~0ull >> (64 - l));
    int base = 0;
    f32x4 o0, o1, o2, o3;
#define EMT(i, vec, c, ov, oc) { u64 beq = __ballot(k##i == T); \
    int rank = base + __popcll(beq & mymask); \
    bool keep = (k##i > T) | ((k##i == T) & (rank < need)); \
    ov[oc] = keep ? vec[c] : 0.0f; \
    base += __popcll(beq); }
    EMT(0, v0, 0, o0, 0)  EMT(1, v0, 1, o0, 1)  EMT(2, v0, 2, o0, 2)  EMT(3, v0, 3, o0, 3)
    EMT(4, v1, 0, o1, 0)  EMT(5, v1, 1, o1, 1)  EMT(6, v1, 2, o1, 2)  EMT(7, v1, 3, o1, 3)
    EMT(8, v2, 0, o2, 0)  EMT(9, v2, 1, o2, 1)  EMT(10, v2, 2, o2, 2) EMT(11, v2, 3, o2, 3)
    EMT(12, v3, 0, o3, 0) EMT(13, v3, 1, o3, 1) EMT(14, v3, 2, o3, 2) EMT(15, v3, 3, o3, 3)
#undef EMT
    float* Ar = A + (size_t)n * NN + l * 16;
    *(f32x4*)(Ar + 0)  = o0;
    *(f32x4*)(Ar + 4)  = o1;
    *(f32x4*)(Ar + 8)  = o2;
    *(f32x4*)(Ar + 12) = o3;
}

// ---------------------------------------------------------------------------
// K3b: deg[d] = sum_s A[s][d]. 32 blocks x 32-row stripes, float4 coalesced
// reads (A is L2/L3-resident), 4 atomicAdds/thread -> 32k atomics (32/addr).
__global__ __launch_bounds__(256) void k_deg(const float* __restrict__ A,
                                             float* __restrict__ deg) {
    const int t = threadIdx.x;
    const int r0 = blockIdx.x * 32;
    f32x4 a = {};
#pragma unroll 4
    for (int r = 0; r < 32; ++r)
        a += *(const f32x4*)&A[(size_t)(r0 + r) * NN + t * 4];
    atomicAdd(&deg[t * 4 + 0], a[0]);
    atomicAdd(&deg[t * 4 + 1], a[1]);
    atomicAdd(&deg[t * 4 + 2], a[2]);
    atomicAdd(&deg[t * 4 + 3], a[3]);
}

// ---------------------------------------------------------------------------
// K5: Atr[d][s] = bf16( A[s][d] * dinv(deg[d]) * dinv(deg[s]) )  (dinv inline)
__global__ __launch_bounds__(256) void k_prescale_tr(const float* __restrict__ A,
                                                     const float* __restrict__ deg,
                                                     ushort_t* __restrict__ Atr) {
    __shared__ float tile[32][33];
    int c0 = blockIdx.x * 32;   // d
    int r0 = blockIdx.y * 32;   // s
    int tx = threadIdx.x, ty = threadIdx.y;
#pragma unroll
    for (int j = 0; j < 32; j += 8)
        tile[ty + j][tx] = A[(size_t)(r0 + ty + j) * NN + c0 + tx];
    __syncthreads();
#pragma unroll
    for (int j = 0; j < 32; j += 8) {
        int d = c0 + ty + j;
        int s = r0 + tx;
        float dd = deg[d], ds_ = deg[s];
        float di = (dd > 0.f) ? (1.0f / sqrtf(dd)) : 0.0f;
        float si = (ds_ > 0.f) ? (1.0f / sqrtf(ds_)) : 0.0f;
        Atr[(size_t)d * NN + s] = f2bf(tile[tx][ty + j] * di * si);
    }
}

// ---------------------------------------------------------------------------
// Generic bf16 NT MFMA GEMM: C[i][j] = sum_k A[i][k]*B[j][k].
// 128x128 tile, BK=32, 2x2 waves acc[4][4], LDS dbuf + global_load_lds,
// swizzled LDS (conflict-free), batched via blockIdx.z.
// bf16out: optional per-column scale cscale[z*NN + col]; fp32 out: +bias[i&255].
__global__ __launch_bounds__(256, 4) void k_mfma_nt(const ushort_t* __restrict__ A,
                                                    const ushort_t* __restrict__ B,
                                                    void* __restrict__ Cv,
                                                    const float* __restrict__ bias,
                                                    const float* __restrict__ cscale,
                                                    int lda, int ldb, int ldc,
                                                    long strA, long strB, long strC,
                                                    int K, int bf16out) {
    __shared__ ushort_t sA[2][4096], sB[2][4096];
    const int t = threadIdx.x, l = t & 63, w = t >> 6;
    const int i0 = blockIdx.y * 128, j0 = blockIdx.x * 128, z = blockIdx.z;
    const ushort_t* Ab = A + (size_t)z * strA;
    const ushort_t* Bb = B + (size_t)z * strB;
    const int ra = t >> 2;
    const int rb = ra + 64;
    const int qa = ((((t & 3) - (ra >> 1)) & 3)) * 8;   // swizzled source quad
    const int lb0 = 512 * w, lb1 = 512 * (w + 4);
    const int wr = (w >> 1) * 64, wc = (w & 1) * 64;
    const int lrow = l & 15, g = l >> 4;

    int offA[4], offB[4];
#pragma unroll
    for (int r = 0; r < 4; ++r) {
        int row = wr + r * 16 + lrow;
        offA[r] = row * 32 + (((g + (row >> 1)) & 3) * 8);
        row = wc + r * 16 + lrow;
        offB[r] = row * 32 + (((g + (row >> 1)) & 3) * 8);
    }

    auto dma = [&](int k0, int buf) {
        gload16(Ab + (size_t)(i0 + ra) * lda + k0 + qa, &sA[buf][lb0]);
        gload16(Ab + (size_t)(i0 + rb) * lda + k0 + qa, &sA[buf][lb1]);
        gload16(Bb + (size_t)(j0 + ra) * ldb + k0 + qa, &sB[buf][lb0]);
        gload16(Bb + (size_t)(j0 + rb) * ldb + k0 + qa, &sB[buf][lb1]);
    };

    f32x4 acc[4][4] = {};
    dma(0, 0);
    for (int k0 = 0; k0 < K; k0 += 32) {
        const int cur = (k0 >> 5) & 1;
        __syncthreads();                        // drains DMA into buf[cur]
        if (k0 + 32 < K) dma(k0 + 32, cur ^ 1); // prefetch next into other buf
        bf16x8 af[4], bf_[4];
#pragma unroll
        for (int r = 0; r < 4; ++r)
            af[r] = *(const bf16x8*)&sA[cur][offA[r]];
#pragma unroll
        for (int c = 0; c < 4; ++c)
            bf_[c] = *(const bf16x8*)&sB[cur][offB[c]];
#pragma unroll
        for (int r = 0; r < 4; ++r)
#pragma unroll
            for (int c = 0; c < 4; ++c)
                acc[r][c] = __builtin_amdgcn_mfma_f32_16x16x32_bf16(af[r], bf_[c], acc[r][c], 0, 0, 0);
    }
    const int orow = i0 + wr + (l >> 4) * 4;
    const int ocol = j0 + wc + lrow;
    if (bf16out) {
        ushort_t* Cp = (ushort_t*)Cv + (size_t)z * strC;
#pragma unroll
        for (int c = 0; c < 4; ++c) {
            float sc = cscale ? cscale[(size_t)z * NN + ocol + c * 16] : 1.0f;
#pragma unroll
            for (int r = 0; r < 4; ++r)
#pragma unroll
                for (int p = 0; p < 4; ++p)
                    Cp[(size_t)(orow + r * 16 + p) * ldc + ocol + c * 16] = f2bf(acc[r][c][p] * sc);
        }
    } else {
        float* Cp = (float*)Cv + (size_t)z * strC;
#pragma unroll
        for (int r = 0; r < 4; ++r)
#pragma unroll
            for (int c = 0; c < 4; ++c)
#pragma unroll
                for (int p = 0; p < 4; ++p) {
                    float bv = bias ? bias[(orow + r * 16 + p) & (LL - 1)] : 0.0f;
                    Cp[(size_t)(orow + r * 16 + p) * ldc + ocol + c * 16] = acc[r][c][p] + bv;
                }
    }
}

// ---------------------------------------------------------------------------
extern "C" void kernel_launch(void* const* d_in, const int* in_sizes, int n_in,
                              void* d_out, int out_size, void* d_ws, size_t ws_size,
                              hipStream_t stream) {
    const float* x      = (const float*)d_in[0];   // [B, L, N]
    const float* weight = (const float*)d_in[1];   // [L, L]
    const float* bias   = (const float*)d_in[2];   // [L]
    float* out = (float*)d_out;                    // [B, L, N] == [bl][d]

    char* p = (char*)d_ws;
    ushort_t* xhi  = (ushort_t*)p; p += (size_t)NN * BL * 2;          // 16.8MB
    ushort_t* xlo  = (ushort_t*)p; p += (size_t)NN * BL * 2;          // 16.8MB
    float*    part = (float*)p;                                        // 37.75MB
    ushort_t* xwT  = (ushort_t*)p;                                     // aliases part (dead before GEMM2)
    p += (size_t)SPLITK * PART_STRIDE * 4;
    ushort_t* Atrb = (ushort_t*)p; p += (size_t)NN * NN * 2;          // 2.1MB
    ushort_t* WTb  = (ushort_t*)p; p += (size_t)LL * LL * 2;          // 128KB
    float* sim  = (float*)p; p += (size_t)NN * NN * 4;                // 4.2MB
    float* Aw   = (float*)p; p += (size_t)NN * NN * 4;                // 4.2MB
    float* deg  = (float*)p; p += NN * 4;
    float* nrm  = (float*)p; p += (size_t)BB * NN * 4;                // 128KB

    // 1. fused: norms + transpose to node-major bf16 hi/lo + fp32 norms
    //    + WT = bf16(W^T) in the blockIdx.x==32 slab (8 dispatches total)
    k_prep<<<dim3(NN / 32 + 1, BB), dim3(256), 0, stream>>>(x, xhi, xlo, nrm, weight, WTb);
    // 2. sim partials (split-bf16 16x16x32 MFMA, 3-phase 32KB-LDS, splitK=16)
    k_sim_mfma<<<dim3(NTILES * SPLITK), 256, 0, stream>>>(xhi, xlo, part);
    // 3. reduce partials -> full sim (mirror fused, 1/B scale)
    k_reduce<<<dim3(NTILES, 4), 256, 0, stream>>>(part, sim);
    // 4. exact top-307 per row -> Aw (block 0 also zeroes deg)
    k_topk<<<dim3(NN / 4), 256, 0, stream>>>(sim, Aw, deg);
    // 4b. deg = column-sum of Aw (32k atomics)
    k_deg<<<dim3(NN / 32), 256, 0, stream>>>(Aw, deg);
    // 5. Atr = bf16(D^-1/2 A^T D^-1/2) with inline rsqrt
    k_prescale_tr<<<dim3(NN / 32, NN / 32), dim3(32, 8), 0, stream>>>(Aw, deg, Atrb);
    // 6. xwT[b*256+o][n] = nrm[b][n] * sum_l WT[o][l] * xhi[n][b*256+l]  (bf16 out)
    k_mfma_nt<<<dim3(NN / 128, LL / 128, BB), 256, 0, stream>>>(
        WTb, xhi, xwT, nullptr, nrm, LL, BL, NN, 0, LL, (long)LL * NN, LL, 1);
    // 7. out[bl][d] = sum_s xwT[bl][s] * Atr[d][s] + bias[bl&255]  (fp32 out)
    k_mfma_nt<<<dim3(NN / 128, BL / 128, 1), 256, 0, stream>>>(
        xwT, Atrb, out, bias, nullptr, NN, NN, NN, 0, 0, 0, NN, 0);
}

// Round 12
// 190.172 us; speedup vs baseline: 1.3638x; 1.3638x over previous
//
#include <hip/hip_runtime.h>

// Problem constants
#define BB 32
#define LL 256
#define NN 1024
#define BL 8192         // B*L
#define TOPK 307        // int(1024*0.3)
#define SPLITK 16
#define NTILES 36       // upper-tri 128x128 tiles of 1024x1024
#define PART_STRIDE ((size_t)NTILES * 16384)

typedef unsigned short ushort_t;
typedef unsigned long long u64;
typedef __bf16 bf16x8 __attribute__((ext_vector_type(8)));
typedef float f32x4 __attribute__((ext_vector_type(4)));
typedef unsigned short us4 __attribute__((ext_vector_type(4)));

// round-to-nearest-even float -> bf16
__device__ __forceinline__ ushort_t f2bf(float f) {
    unsigned int u = __float_as_uint(f);
    u += 0x7FFFu + ((u >> 16) & 1u);
    return (ushort_t)(u >> 16);
}
__device__ __forceinline__ float bf2f(ushort_t h) {
    return __uint_as_float(((unsigned int)h) << 16);
}

// async global->LDS DMA, 16B/lane; LDS dest = wave-uniform base + lane*16
__device__ __forceinline__ void gload16(const void* g, const void* l) {
    __builtin_amdgcn_global_load_lds(
        (__attribute__((address_space(1))) void*)(unsigned long long)g,
        (__attribute__((address_space(3))) void*)(unsigned int)(unsigned long long)l,
        16, 0, 0);
}

// LDS bank-conflict swizzle: LDS (row, quad-slot qp) holds global k-quad
// g = (qp - (row>>1)) & 3. Writer thread t (row=t>>2, qp=t&3) sources quad
// ((t&3) - ((t>>2)>>1)) & 3; rows +64 give the same value (32 ≡ 0 mod 4).
// Reader: slot for quad g of row r is (g + (r>>1)) & 3 -> conflict-free for
// the 16x16 fragment read (measured 0 SQ_LDS_BANK_CONFLICT).
// LESSONS (measured, do not retry):
//  - 32x32x16 MFMA under this swizzle: 2.36M bank conflicts, net regression (R9).
//  - 3-phase LDS-halving (hi/lo split passes): 3x HBM re-stream, FETCH 20->110MB,
//    k_sim 43->110us (R11). All 4 operand arrays MUST be co-staged.
//  - fp16 single-pass sim: top-k membership flips, absmax fail (R6).

// ---------------------------------------------------------------------------
// K1 (fused norms + transpose): one pass over x. Emits node-major bf16 xhi/xlo
// (normalized hi/lo split) and fp32 nrm[b][n]. ushort4 write phase.
// Extra slab blockIdx.x==32: WT[o][l] = bf16(W[l][o]) (fused to cut a dispatch).
__global__ __launch_bounds__(256) void k_prep(const float* __restrict__ x,
                                              ushort_t* __restrict__ xhi,
                                              ushort_t* __restrict__ xlo,
                                              float* __restrict__ nrm,
                                              const float* __restrict__ W,
                                              ushort_t* __restrict__ WT) {
    __shared__ float tile[32][268];   // [n_local][l], 268: %32=12 (<=4-way), 16B-aligned rows
    __shared__ float red[32][33];     // [lr][n_local]
    __shared__ float inv[32];
    __shared__ float wt[32][33];
    const int t = threadIdx.x;
    if (blockIdx.x == 32) {           // W^T slab: 32 blocks x 2 tiles of 32x32
        const int tx = t & 31, ty = t >> 5;
#pragma unroll
        for (int s = 0; s < 2; ++s) {
            const int id = blockIdx.y * 2 + s;   // [0,64)
            const int c0 = (id & 7) * 32;        // o
            const int r0 = (id >> 3) * 32;       // l
#pragma unroll
            for (int j = 0; j < 32; j += 8)
                wt[ty + j][tx] = W[(size_t)(r0 + ty + j) * LL + c0 + tx];
            __syncthreads();
#pragma unroll
            for (int j = 0; j < 32; j += 8)
                WT[(size_t)(c0 + ty + j) * LL + r0 + tx] = f2bf(wt[tx][ty + j]);
            __syncthreads();
        }
        return;
    }
    const int n0 = blockIdx.x * 32, b = blockIdx.y;
    const int qn = (t & 7) * 4, lr = t >> 3;
    const float* xb = x + (size_t)b * LL * NN + n0;
    float p0 = 0.f, p1 = 0.f, p2 = 0.f, p3 = 0.f;
#pragma unroll
    for (int j = 0; j < 8; ++j) {
        int l = lr + 32 * j;
        f32x4 v = *(const f32x4*)&xb[(size_t)l * NN + qn];
        tile[qn + 0][l] = v[0];
        tile[qn + 1][l] = v[1];
        tile[qn + 2][l] = v[2];
        tile[qn + 3][l] = v[3];
        p0 = fmaf(v[0], v[0], p0);
        p1 = fmaf(v[1], v[1], p1);
        p2 = fmaf(v[2], v[2], p2);
        p3 = fmaf(v[3], v[3], p3);
    }
    red[lr][qn + 0] = p0;
    red[lr][qn + 1] = p1;
    red[lr][qn + 2] = p2;
    red[lr][qn + 3] = p3;
    __syncthreads();
    if (t < 32) {
        float acc = 0.f;
#pragma unroll
        for (int j = 0; j < 32; ++j) acc += red[j][t];
        float nv = fmaxf(sqrtf(acc), 1e-12f);
        nrm[b * NN + n0 + t] = nv;
        inv[t] = 1.0f / nv;
    }
    __syncthreads();
    // write phase: thread handles 4 consecutive l (ushort4 stores), 8 n per wave
    const int l4 = (t & 63) * 4, wv = t >> 6;
#pragma unroll
    for (int j = 0; j < 8; ++j) {
        const int nl = wv * 8 + j;
        f32x4 v = *(const f32x4*)&tile[nl][l4];
        const float iv = inv[nl];
        us4 hi, lo;
#pragma unroll
        for (int i = 0; i < 4; ++i) {
            float sc = v[i] * iv;
            ushort_t h = f2bf(sc);
            hi[i] = h;
            lo[i] = f2bf(sc - bf2f(h));
        }
        size_t o = (size_t)(n0 + nl) * BL + b * LL + l4;
        *(us4*)&xhi[o] = hi;
        *(us4*)&xlo[o] = lo;
    }
}

// ---------------------------------------------------------------------------
// GEMM1: partial sims, split-bf16 (hi*hi + hi*lo + lo*hi), 16x16x32 MFMA.
// All 4 operand arrays co-staged (64KB dbuf), 2 blocks/CU. Upper-tri
// 128-tiles, splitK=16, LDS dbuf + XCD swizzle (FETCH ~20MB, L2-resident).
// Proven operating point: ~43us, MfmaUtil 25%, 0 bank conflicts.
__global__ __launch_bounds__(256, 2) void k_sim_mfma(const ushort_t* __restrict__ Xhi,
                                                     const ushort_t* __restrict__ Xlo,
                                                     float* __restrict__ part) {
    __shared__ ushort_t sAh[2][4096], sAl[2][4096];
    __shared__ ushort_t sBh[2][4096], sBl[2][4096];
    const int t = threadIdx.x, l = t & 63, w = t >> 6;
    const int bid = blockIdx.x;
    const int swz = (bid & 7) * 72 + (bid >> 3);   // bijective: 576 = 8*72
    const int z = swz / NTILES;
    const int tid36 = swz - z * NTILES;
    int id = tid36, ti = 0;                    // [0,36) -> upper-tri (ti,tj)
    while (id >= 8 - ti) { id -= 8 - ti; ++ti; }
    const int tj = ti + id;
    const int i0 = ti * 128, j0 = tj * 128;
    const int it0 = 16 * z, it1 = it0 + 16;
    const int ra = t >> 2;
    const int rb = ra + 64;
    const int qa = ((((t & 3) - (ra >> 1)) & 3)) * 8;   // swizzled source quad
    const int lb0 = 512 * w, lb1 = 512 * (w + 4);
    const int wr = (w >> 1) * 64, wc = (w & 1) * 64;
    const int lrow = l & 15, g = l >> 4;
    const ushort_t* Ah = Xhi + (size_t)i0 * BL;
    const ushort_t* Al = Xlo + (size_t)i0 * BL;
    const ushort_t* Bh = Xhi + (size_t)j0 * BL;
    const ushort_t* Bl = Xlo + (size_t)j0 * BL;

    // hoisted swizzled fragment offsets
    int offA[4], offB[4];
#pragma unroll
    for (int r = 0; r < 4; ++r) {
        int row = wr + r * 16 + lrow;
        offA[r] = row * 32 + (((g + (row >> 1)) & 3) * 8);
        row = wc + r * 16 + lrow;
        offB[r] = row * 32 + (((g + (row >> 1)) & 3) * 8);
    }

    auto dma = [&](int it, int buf) {
        const int k0 = it * 32;
        gload16(Ah + (size_t)ra * BL + k0 + qa, &sAh[buf][lb0]);
        gload16(Ah + (size_t)rb * BL + k0 + qa, &sAh[buf][lb1]);
        gload16(Al + (size_t)ra * BL + k0 + qa, &sAl[buf][lb0]);
        gload16(Al + (size_t)rb * BL + k0 + qa, &sAl[buf][lb1]);
        gload16(Bh + (size_t)ra * BL + k0 + qa, &sBh[buf][lb0]);
        gload16(Bh + (size_t)rb * BL + k0 + qa, &sBh[buf][lb1]);
        gload16(Bl + (size_t)ra * BL + k0 + qa, &sBl[buf][lb0]);
        gload16(Bl + (size_t)rb * BL + k0 + qa, &sBl[buf][lb1]);
    };

    f32x4 acc[4][4] = {};
    dma(it0, 0);
    for (int it = it0; it < it1; ++it) {
        const int cur = (it - it0) & 1;
        __syncthreads();                         // drains DMA into buf[cur]
        if (it + 1 < it1) dma(it + 1, cur ^ 1);  // prefetch next into other buf
        bf16x8 ah[4], al[4], bh[4], bl[4];
#pragma unroll
        for (int r = 0; r < 4; ++r) {
            ah[r] = *(const bf16x8*)&sAh[cur][offA[r]];
            al[r] = *(const bf16x8*)&sAl[cur][offA[r]];
        }
#pragma unroll
        for (int c = 0; c < 4; ++c) {
            bh[c] = *(const bf16x8*)&sBh[cur][offB[c]];
            bl[c] = *(const bf16x8*)&sBl[cur][offB[c]];
        }
#pragma unroll
        for (int r = 0; r < 4; ++r)
#pragma unroll
            for (int c = 0; c < 4; ++c) {
                acc[r][c] = __builtin_amdgcn_mfma_f32_16x16x32_bf16(ah[r], bh[c], acc[r][c], 0, 0, 0);
                acc[r][c] = __builtin_amdgcn_mfma_f32_16x16x32_bf16(ah[r], bl[c], acc[r][c], 0, 0, 0);
                acc[r][c] = __builtin_amdgcn_mfma_f32_16x16x32_bf16(al[r], bh[c], acc[r][c], 0, 0, 0);
            }
    }
    float* P = part + (size_t)z * PART_STRIDE + (size_t)tid36 * 16384;
    const int orow = wr + (l >> 4) * 4;
    const int ocol = wc + lrow;
#pragma unroll
    for (int r = 0; r < 4; ++r)
#pragma unroll
        for (int c = 0; c < 4; ++c)
#pragma unroll
            for (int p = 0; p < 4; ++p)
                P[(size_t)(orow + r * 16 + p) * 128 + ocol + c * 16] = acc[r][c][p];
}

// ---------------------------------------------------------------------------
// Reduce partials -> sim (both triangles, scaled by 1/B). float4 I/O.
__global__ __launch_bounds__(256) void k_reduce(const float* __restrict__ part,
                                                float* __restrict__ sim) {
    __shared__ float tl[64][65];
    const int t = threadIdx.x;
    int id = blockIdx.x, ti = 0;
    while (id >= 8 - ti) { id -= 8 - ti; ++ti; }
    const int tj = ti + id;
    const int q = blockIdx.y;
    const int r0 = (q >> 1) * 64, c0 = (q & 1) * 64;
    const float* Pu = part + (size_t)blockIdx.x * 16384;
    const int fr = t & 15, rq = t >> 4;   // fr: float4-col, rq: row within 16
#pragma unroll
    for (int e = 0; e < 4; ++e) {
        int r = e * 16 + rq;
        f32x4 s = {};
#pragma unroll
        for (int z = 0; z < SPLITK; ++z)
            s += *(const f32x4*)&Pu[(size_t)z * PART_STRIDE + (size_t)(r0 + r) * 128 + c0 + fr * 4];
        s *= (1.0f / BB);
        *(f32x4*)&sim[(size_t)(ti * 128 + r0 + r) * NN + tj * 128 + c0 + fr * 4] = s;
        tl[r][fr * 4 + 0] = s[0];
        tl[r][fr * 4 + 1] = s[1];
        tl[r][fr * 4 + 2] = s[2];
        tl[r][fr * 4 + 3] = s[3];
    }
    __syncthreads();
    if (ti != tj) {
#pragma unroll
        for (int e = 0; e < 16; ++e) {
            int li = e * 256 + t;
            int cc = li >> 6, rr = li & 63;   // rr consecutive -> coalesced
            sim[(size_t)(tj * 128 + c0 + cc) * NN + ti * 128 + r0 + rr] = tl[rr][cc];
        }
    }
}

// ---------------------------------------------------------------------------
// K3: exact top-307 per row (excl self), one wave/row, ballot binary search.
// Named scalars (register-resident), float4 I/O. Block 0 also zeroes deg
// (replaces a hipMemsetAsync dispatch; stream order covers k_deg's atomics).
#define FOR16(M) M(0) M(1) M(2) M(3) M(4) M(5) M(6) M(7) \
                 M(8) M(9) M(10) M(11) M(12) M(13) M(14) M(15)
__global__ __launch_bounds__(256, 1) void k_topk(const float* __restrict__ sim,
                                                 float* __restrict__ A,
                                                 float* __restrict__ deg) {
    const int t = threadIdx.x, l = t & 63, w = t >> 6;
    if (blockIdx.x == 0) {
        f32x4 zz = {};
        *(f32x4*)&deg[t * 4] = zz;
    }
    const int n = blockIdx.x * 4 + w;
    const float* row = sim + (size_t)n * NN + l * 16;
    f32x4 v0 = *(const f32x4*)(row + 0);
    f32x4 v1 = *(const f32x4*)(row + 4);
    f32x4 v2 = *(const f32x4*)(row + 8);
    f32x4 v3 = *(const f32x4*)(row + 12);
    const int selfe = n - l * 16;   // in [0,16) iff this lane holds the diagonal
#define MKK(i, vec, c) unsigned k##i; { unsigned u = __float_as_uint(vec[c]); \
    unsigned kk = (u & 0x80000000u) ? ~u : (u | 0x80000000u); \
    k##i = (selfe == i) ? 0u : kk; }
    MKK(0, v0, 0)  MKK(1, v0, 1)  MKK(2, v0, 2)  MKK(3, v0, 3)
    MKK(4, v1, 0)  MKK(5, v1, 1)  MKK(6, v1, 2)  MKK(7, v1, 3)
    MKK(8, v2, 0)  MKK(9, v2, 1)  MKK(10, v2, 2) MKK(11, v2, 3)
    MKK(12, v3, 0) MKK(13, v3, 1) MKK(14, v3, 2) MKK(15, v3, 3)
#undef MKK
    unsigned cur = 0u;
    for (int bit = 31; bit >= 0; --bit) {
        unsigned cand = cur | (1u << bit);
        int c = 0;
#define CNT(i) c += __popcll(__ballot(k##i >= cand));
        FOR16(CNT)
#undef CNT
        if (c >= TOPK) cur = cand;
    }
    const unsigned T = cur;
    int cgt = 0;
#define CGT(i) cgt += __popcll(__ballot(k##i > T));
    FOR16(CGT)
#undef CGT
    const int need = TOPK - cgt;
    const u64 mymask = (l == 0) ? 0ull : (~0ull >> (64 - l));
    int base = 0;
    f32x4 o0, o1, o2, o3;
#define EMT(i, vec, c, ov, oc) { u64 beq = __ballot(k##i == T); \
    int rank = base + __popcll(beq & mymask); \
    bool keep = (k##i > T) | ((k##i == T) & (rank < need)); \
    ov[oc] = keep ? vec[c] : 0.0f; \
    base += __popcll(beq); }
    EMT(0, v0, 0, o0, 0)  EMT(1, v0, 1, o0, 1)  EMT(2, v0, 2, o0, 2)  EMT(3, v0, 3, o0, 3)
    EMT(4, v1, 0, o1, 0)  EMT(5, v1, 1, o1, 1)  EMT(6, v1, 2, o1, 2)  EMT(7, v1, 3, o1, 3)
    EMT(8, v2, 0, o2, 0)  EMT(9, v2, 1, o2, 1)  EMT(10, v2, 2, o2, 2) EMT(11, v2, 3, o2, 3)
    EMT(12, v3, 0, o3, 0) EMT(13, v3, 1, o3, 1) EMT(14, v3, 2, o3, 2) EMT(15, v3, 3, o3, 3)
#undef EMT
    float* Ar = A + (size_t)n * NN + l * 16;
    *(f32x4*)(Ar + 0)  = o0;
    *(f32x4*)(Ar + 4)  = o1;
    *(f32x4*)(Ar + 8)  = o2;
    *(f32x4*)(Ar + 12) = o3;
}

// ---------------------------------------------------------------------------
// K3b: deg[d] = sum_s A[s][d]. 32 blocks x 32-row stripes, float4 coalesced
// reads (A is L2/L3-resident), 4 atomicAdds/thread -> 32k atomics (32/addr).
__global__ __launch_bounds__(256) void k_deg(const float* __restrict__ A,
                                             float* __restrict__ deg) {
    const int t = threadIdx.x;
    const int r0 = blockIdx.x * 32;
    f32x4 a = {};
#pragma unroll 4
    for (int r = 0; r < 32; ++r)
        a += *(const f32x4*)&A[(size_t)(r0 + r) * NN + t * 4];
    atomicAdd(&deg[t * 4 + 0], a[0]);
    atomicAdd(&deg[t * 4 + 1], a[1]);
    atomicAdd(&deg[t * 4 + 2], a[2]);
    atomicAdd(&deg[t * 4 + 3], a[3]);
}

// ---------------------------------------------------------------------------
// K5: Atr[d][s] = bf16( A[s][d] * dinv(deg[d]) * dinv(deg[s]) )  (dinv inline)
__global__ __launch_bounds__(256) void k_prescale_tr(const float* __restrict__ A,
                                                     const float* __restrict__ deg,
                                                     ushort_t* __restrict__ Atr) {
    __shared__ float tile[32][33];
    int c0 = blockIdx.x * 32;   // d
    int r0 = blockIdx.y * 32;   // s
    int tx = threadIdx.x, ty = threadIdx.y;
#pragma unroll
    for (int j = 0; j < 32; j += 8)
        tile[ty + j][tx] = A[(size_t)(r0 + ty + j) * NN + c0 + tx];
    __syncthreads();
#pragma unroll
    for (int j = 0; j < 32; j += 8) {
        int d = c0 + ty + j;
        int s = r0 + tx;
        float dd = deg[d], ds_ = deg[s];
        float di = (dd > 0.f) ? (1.0f / sqrtf(dd)) : 0.0f;
        float si = (ds_ > 0.f) ? (1.0f / sqrtf(ds_)) : 0.0f;
        Atr[(size_t)d * NN + s] = f2bf(tile[tx][ty + j] * di * si);
    }
}

// ---------------------------------------------------------------------------
// Generic bf16 NT MFMA GEMM: C[i][j] = sum_k A[i][k]*B[j][k].
// 128x128 tile, BK=32, 2x2 waves acc[4][4], LDS dbuf + global_load_lds,
// swizzled LDS (conflict-free), batched via blockIdx.z.
// bf16out: optional per-column scale cscale[z*NN + col]; fp32 out: +bias[i&255].
__global__ __launch_bounds__(256, 4) void k_mfma_nt(const ushort_t* __restrict__ A,
                                                    const ushort_t* __restrict__ B,
                                                    void* __restrict__ Cv,
                                                    const float* __restrict__ bias,
                                                    const float* __restrict__ cscale,
                                                    int lda, int ldb, int ldc,
                                                    long strA, long strB, long strC,
                                                    int K, int bf16out) {
    __shared__ ushort_t sA[2][4096], sB[2][4096];
    const int t = threadIdx.x, l = t & 63, w = t >> 6;
    const int i0 = blockIdx.y * 128, j0 = blockIdx.x * 128, z = blockIdx.z;
    const ushort_t* Ab = A + (size_t)z * strA;
    const ushort_t* Bb = B + (size_t)z * strB;
    const int ra = t >> 2;
    const int rb = ra + 64;
    const int qa = ((((t & 3) - (ra >> 1)) & 3)) * 8;   // swizzled source quad
    const int lb0 = 512 * w, lb1 = 512 * (w + 4);
    const int wr = (w >> 1) * 64, wc = (w & 1) * 64;
    const int lrow = l & 15, g = l >> 4;

    int offA[4], offB[4];
#pragma unroll
    for (int r = 0; r < 4; ++r) {
        int row = wr + r * 16 + lrow;
        offA[r] = row * 32 + (((g + (row >> 1)) & 3) * 8);
        row = wc + r * 16 + lrow;
        offB[r] = row * 32 + (((g + (row >> 1)) & 3) * 8);
    }

    auto dma = [&](int k0, int buf) {
        gload16(Ab + (size_t)(i0 + ra) * lda + k0 + qa, &sA[buf][lb0]);
        gload16(Ab + (size_t)(i0 + rb) * lda + k0 + qa, &sA[buf][lb1]);
        gload16(Bb + (size_t)(j0 + ra) * ldb + k0 + qa, &sB[buf][lb0]);
        gload16(Bb + (size_t)(j0 + rb) * ldb + k0 + qa, &sB[buf][lb1]);
    };

    f32x4 acc[4][4] = {};
    dma(0, 0);
    for (int k0 = 0; k0 < K; k0 += 32) {
        const int cur = (k0 >> 5) & 1;
        __syncthreads();                        // drains DMA into buf[cur]
        if (k0 + 32 < K) dma(k0 + 32, cur ^ 1); // prefetch next into other buf
        bf16x8 af[4], bf_[4];
#pragma unroll
        for (int r = 0; r < 4; ++r)
            af[r] = *(const bf16x8*)&sA[cur][offA[r]];
#pragma unroll
        for (int c = 0; c < 4; ++c)
            bf_[c] = *(const bf16x8*)&sB[cur][offB[c]];
#pragma unroll
        for (int r = 0; r < 4; ++r)
#pragma unroll
            for (int c = 0; c < 4; ++c)
                acc[r][c] = __builtin_amdgcn_mfma_f32_16x16x32_bf16(af[r], bf_[c], acc[r][c], 0, 0, 0);
    }
    const int orow = i0 + wr + (l >> 4) * 4;
    const int ocol = j0 + wc + lrow;
    if (bf16out) {
        ushort_t* Cp = (ushort_t*)Cv + (size_t)z * strC;
#pragma unroll
        for (int c = 0; c < 4; ++c) {
            float sc = cscale ? cscale[(size_t)z * NN + ocol + c * 16] : 1.0f;
#pragma unroll
            for (int r = 0; r < 4; ++r)
#pragma unroll
                for (int p = 0; p < 4; ++p)
                    Cp[(size_t)(orow + r * 16 + p) * ldc + ocol + c * 16] = f2bf(acc[r][c][p] * sc);
        }
    } else {
        float* Cp = (float*)Cv + (size_t)z * strC;
#pragma unroll
        for (int r = 0; r < 4; ++r)
#pragma unroll
            for (int c = 0; c < 4; ++c)
#pragma unroll
                for (int p = 0; p < 4; ++p) {
                    float bv = bias ? bias[(orow + r * 16 + p) & (LL - 1)] : 0.0f;
                    Cp[(size_t)(orow + r * 16 + p) * ldc + ocol + c * 16] = acc[r][c][p] + bv;
                }
    }
}

// ---------------------------------------------------------------------------
extern "C" void kernel_launch(void* const* d_in, const int* in_sizes, int n_in,
                              void* d_out, int out_size, void* d_ws, size_t ws_size,
                              hipStream_t stream) {
    const float* x      = (const float*)d_in[0];   // [B, L, N]
    const float* weight = (const float*)d_in[1];   // [L, L]
    const float* bias   = (const float*)d_in[2];   // [L]
    float* out = (float*)d_out;                    // [B, L, N] == [bl][d]

    char* p = (char*)d_ws;
    ushort_t* xhi  = (ushort_t*)p; p += (size_t)NN * BL * 2;          // 16.8MB
    ushort_t* xlo  = (ushort_t*)p; p += (size_t)NN * BL * 2;          // 16.8MB
    float*    part = (float*)p;                                        // 37.75MB
    ushort_t* xwT  = (ushort_t*)p;                                     // aliases part (dead before GEMM2)
    p += (size_t)SPLITK * PART_STRIDE * 4;
    ushort_t* Atrb = (ushort_t*)p; p += (size_t)NN * NN * 2;          // 2.1MB
    ushort_t* WTb  = (ushort_t*)p; p += (size_t)LL * LL * 2;          // 128KB
    float* sim  = (float*)p; p += (size_t)NN * NN * 4;                // 4.2MB
    float* Aw   = (float*)p; p += (size_t)NN * NN * 4;                // 4.2MB
    float* deg  = (float*)p; p += NN * 4;
    float* nrm  = (float*)p; p += (size_t)BB * NN * 4;                // 128KB

    // 1. fused: norms + transpose to node-major bf16 hi/lo + fp32 norms
    //    + WT = bf16(W^T) in the blockIdx.x==32 slab (8 dispatches total)
    k_prep<<<dim3(NN / 32 + 1, BB), dim3(256), 0, stream>>>(x, xhi, xlo, nrm, weight, WTb);
    // 2. sim partials (split-bf16 16x16x32 MFMA, upper-tri tiles, splitK=16)
    k_sim_mfma<<<dim3(NTILES * SPLITK), 256, 0, stream>>>(xhi, xlo, part);
    // 3. reduce partials -> full sim (mirror fused, 1/B scale)
    k_reduce<<<dim3(NTILES, 4), 256, 0, stream>>>(part, sim);
    // 4. exact top-307 per row -> Aw (block 0 also zeroes deg)
    k_topk<<<dim3(NN / 4), 256, 0, stream>>>(sim, Aw, deg);
    // 4b. deg = column-sum of Aw (32k atomics)
    k_deg<<<dim3(NN / 32), 256, 0, stream>>>(Aw, deg);
    // 5. Atr = bf16(D^-1/2 A^T D^-1/2) with inline rsqrt
    k_prescale_tr<<<dim3(NN / 32, NN / 32), dim3(32, 8), 0, stream>>>(Aw, deg, Atrb);
    // 6. xwT[b*256+o][n] = nrm[b][n] * sum_l WT[o][l] * xhi[n][b*256+l]  (bf16 out)
    k_mfma_nt<<<dim3(NN / 128, LL / 128, BB), 256, 0, stream>>>(
        WTb, xhi, xwT, nullptr, nrm, LL, BL, NN, 0, LL, (long)LL * NN, LL, 1);
    // 7. out[bl][d] = sum_s xwT[bl][s] * Atr[d][s] + bias[bl&255]  (fp32 out)
    k_mfma_nt<<<dim3(NN / 128, BL / 128, 1), 256, 0, stream>>>(
        xwT, Atrb, out, bias, nullptr, NN, NN, NN, 0, 0, 0, NN, 0);
}